// Round 1
// baseline (2888.430 us; speedup 1.0000x reference)
//
#include <hip/hip_runtime.h>
#include <math.h>

#define B_  8
#define C_  256
#define NS_ 16384
#define NT_ 8192
#define H_  8
#define D_  32
#define C2_ 512
#define KVZ_ (H_*D_*D_ + H_*D_)   // 8448 floats per batch (KV + Ksum)

// ---------------------------------------------------------------------------
// pos = relu(xyz @ w1 + b1) @ w2 + b2     xyz: [B,NT,3], out pos: [G,NT,C]
// block: 256 threads = one column each, 16 rows per block. grid (NT/16, G)
__global__ __launch_bounds__(256)
void pos_kernel(const float* __restrict__ xyz, const float* __restrict__ w1,
                const float* __restrict__ b1, const float* __restrict__ w2,
                const float* __restrict__ b2, float* __restrict__ pos, int b0)
{
    __shared__ float hs[16][C_];
    int g = blockIdx.y, gb = b0 + g;
    int r0 = blockIdx.x * 16;
    int t  = threadIdx.x;
    float w1x = w1[0*C_ + t], w1y = w1[1*C_ + t], w1z = w1[2*C_ + t];
    float bb1 = b1[t];
    for (int r = 0; r < 16; ++r) {
        const float* p = xyz + ((size_t)gb*NT_ + r0 + r)*3;
        float h = p[0]*w1x + p[1]*w1y + p[2]*w1z + bb1;
        hs[r][t] = fmaxf(h, 0.f);
    }
    __syncthreads();
    float acc[16];
    #pragma unroll
    for (int r = 0; r < 16; ++r) acc[r] = 0.f;
    for (int j = 0; j < C_; ++j) {
        float w = w2[(size_t)j*C_ + t];
        #pragma unroll
        for (int r = 0; r < 16; ++r) acc[r] += hs[r][j] * w;
    }
    float bb2 = b2[t];
    for (int r = 0; r < 16; ++r)
        pos[((size_t)g*NT_ + r0 + r)*C_ + t] = acc[r] + bb2;
}

// ---------------------------------------------------------------------------
// Generic tiled f32 GEMM: out[g,r,n] = epi( sum_k A(g,r,k) * W[k,n] )
// AMODE 0: A row-major in ws:              A0[(g*M+r)*K + k]
// AMODE 1: transposed feature input:       A0[((b0+g)*C + k)*M + r]
// AMODE 2: transposed feature + ws pos:    mode1 + A1[(g*M+r)*C + k]
// AMODE 3: concat: k<C -> mode1 on A0 ; k>=C -> row-major A1[(g*M+r)*C + k-C]
// EPI 0: none, 1: relu, 2: elu+1
// block 256 threads, 64x64 tile, BK=16, 4x4 micro-tile. grid (M/64, N/64, G)
template<int AMODE, int EPI>
__global__ __launch_bounds__(256)
void gemm_k(const float* __restrict__ A0, const float* __restrict__ A1,
            const float* __restrict__ W, float* __restrict__ out,
            int M, int N, int K, int b0)
{
    __shared__ float As[16][68];
    __shared__ float Ws[16][68];
    int g = blockIdx.z, gb = b0 + g;
    int rbase = blockIdx.x * 64;
    int nbase = blockIdx.y * 64;
    int t = threadIdx.x;
    int tx = t & 15, ty = t >> 4;
    float acc[4][4];
    #pragma unroll
    for (int i = 0; i < 4; ++i)
        #pragma unroll
        for (int j = 0; j < 4; ++j) acc[i][j] = 0.f;

    for (int kb = 0; kb < K; kb += 16) {
        {   // W tile (row-major [K,N], coalesced along n)
            int n = t & 63, k0 = t >> 6;
            #pragma unroll
            for (int i = 0; i < 4; ++i)
                Ws[k0 + 4*i][n] = W[(size_t)(kb + k0 + 4*i)*N + nbase + n];
        }
        if constexpr (AMODE == 0) {
            int r = t >> 2, kq = t & 3;
            float4 v = *(const float4*)(A0 + ((size_t)g*M + rbase + r)*K + kb + kq*4);
            As[kq*4+0][r] = v.x; As[kq*4+1][r] = v.y;
            As[kq*4+2][r] = v.z; As[kq*4+3][r] = v.w;
        } else if constexpr (AMODE == 1) {
            int r = t & 63, k0 = t >> 6;
            #pragma unroll
            for (int i = 0; i < 4; ++i)
                As[k0+4*i][r] = A0[((size_t)gb*C_ + kb + k0 + 4*i)*(size_t)M + rbase + r];
        } else if constexpr (AMODE == 2) {
            int r = t & 63, k0 = t >> 6;
            #pragma unroll
            for (int i = 0; i < 4; ++i) {
                int kk = kb + k0 + 4*i;
                As[k0+4*i][r] = A0[((size_t)gb*C_ + kk)*(size_t)M + rbase + r]
                              + A1[((size_t)g*M + rbase + r)*C_ + kk];
            }
        } else {  // AMODE 3
            if (kb < C_) {
                int r = t & 63, k0 = t >> 6;
                #pragma unroll
                for (int i = 0; i < 4; ++i)
                    As[k0+4*i][r] = A0[((size_t)gb*C_ + kb + k0 + 4*i)*(size_t)M + rbase + r];
            } else {
                int r = t >> 2, kq = t & 3;
                float4 v = *(const float4*)(A1 + ((size_t)g*M + rbase + r)*C_ + (kb - C_) + kq*4);
                As[kq*4+0][r] = v.x; As[kq*4+1][r] = v.y;
                As[kq*4+2][r] = v.z; As[kq*4+3][r] = v.w;
            }
        }
        __syncthreads();
        #pragma unroll
        for (int kk = 0; kk < 16; ++kk) {
            float4 a = *(const float4*)&As[kk][ty*4];
            float4 w = *(const float4*)&Ws[kk][tx*4];
            float av[4] = {a.x, a.y, a.z, a.w};
            float wv[4] = {w.x, w.y, w.z, w.w};
            #pragma unroll
            for (int i = 0; i < 4; ++i)
                #pragma unroll
                for (int j = 0; j < 4; ++j)
                    acc[i][j] += av[i] * wv[j];
        }
        __syncthreads();
    }
    #pragma unroll
    for (int i = 0; i < 4; ++i) {
        size_t ro = ((size_t)g*M + rbase + ty*4 + i)*(size_t)N + nbase;
        #pragma unroll
        for (int j = 0; j < 4; ++j) {
            float v = acc[i][j];
            if constexpr (EPI == 1) v = fmaxf(v, 0.f);
            if constexpr (EPI == 2) v = (v > 0.f) ? (v + 1.f) : expf(v);
            out[ro + tx*4 + j] = v;
        }
    }
}

// ---------------------------------------------------------------------------
// KV[h,d,vd] = sum_s K[s,h,d]*V[s,h,vd];  Ksum[h,d] = sum_s K[s,h,d]
// one block per (h, g). grid (H, G)
__global__ __launch_bounds__(256)
void kv_kernel(const float* __restrict__ Kb, const float* __restrict__ Vb,
               float* __restrict__ kvz)
{
    __shared__ float SK[32][D_];
    __shared__ float SV[32][D_];
    int h = blockIdx.x, g = blockIdx.y;
    int t = threadIdx.x;
    int d = t >> 3, v0 = (t & 7) * 4;
    int lr = t >> 3, lc = (t & 7) * 4;
    float acc[4] = {0.f, 0.f, 0.f, 0.f};
    float ksum = 0.f;
    for (int s0 = 0; s0 < NT_; s0 += 32) {
        size_t off = ((size_t)g*NT_ + s0 + lr)*C_ + h*D_ + lc;
        *(float4*)&SK[lr][lc] = *(const float4*)(Kb + off);
        *(float4*)&SV[lr][lc] = *(const float4*)(Vb + off);
        __syncthreads();
        #pragma unroll
        for (int ss = 0; ss < 32; ++ss) {
            float kd = SK[ss][d];
            #pragma unroll
            for (int j = 0; j < 4; ++j) acc[j] += kd * SV[ss][v0 + j];
            ksum += kd;
        }
        __syncthreads();
    }
    float* KV = kvz + (size_t)g*KVZ_;
    #pragma unroll
    for (int j = 0; j < 4; ++j) KV[h*D_*D_ + d*D_ + v0 + j] = acc[j];
    if ((t & 7) == 0) KV[H_*D_*D_ + h*D_ + d] = ksum;
}

// ---------------------------------------------------------------------------
// msg[l, h*D+vd] = (sum_d Q[l,h,d]*KV[h,d,vd]) / (sum_d Q[l,h,d]*Ksum[h,d] + eps)
// block 256 threads = all C columns; 16 rows per block. grid (NS/16, G)
__global__ __launch_bounds__(256)
void attn_kernel(const float* __restrict__ Qb, const float* __restrict__ kvz,
                 float* __restrict__ msg)
{
    __shared__ float KVs[H_*D_*D_];
    __shared__ float KSs[H_*D_];
    __shared__ float Qs[16][C_];
    int g = blockIdx.y;
    int r0 = blockIdx.x * 16;
    int t = threadIdx.x;
    const float* kvg = kvz + (size_t)g*KVZ_;
    for (int i = t; i < H_*D_*D_; i += 256) KVs[i] = kvg[i];
    KSs[t] = kvg[H_*D_*D_ + t];
    {
        int r = t >> 4, c0 = (t & 15) * 4;
        #pragma unroll
        for (int j = 0; j < 4; ++j)
            *(float4*)&Qs[r][c0 + 64*j] =
                *(const float4*)(Qb + ((size_t)g*NS_ + r0 + r)*C_ + c0 + 64*j);
    }
    __syncthreads();
    int h = t >> 5, vd = t & 31;
    const float* kvh = &KVs[h*D_*D_];
    const float* ksh = &KSs[h*D_];
    for (int rr = 0; rr < 16; ++rr) {
        float qk = 0.f, qv = 0.f;
        #pragma unroll
        for (int d = 0; d < D_; ++d) {
            float q = Qs[rr][h*D_ + d];
            qk += q * ksh[d];
            qv += q * kvh[d*D_ + vd];
        }
        msg[((size_t)g*NS_ + r0 + rr)*C_ + t] = qv / (qk + 1e-6f);
    }
}

// ---------------------------------------------------------------------------
// in-place LayerNorm over last dim C. one 64-lane wave per row. grid (rows/4)
__global__ __launch_bounds__(256)
void ln_kernel(float* __restrict__ x, const float* __restrict__ gam,
               const float* __restrict__ bet)
{
    int row  = blockIdx.x * 4 + (threadIdx.x >> 6);
    int lane = threadIdx.x & 63;
    float* xr = x + (size_t)row*C_;
    float4 v = *(const float4*)(xr + lane*4);
    float s = v.x + v.y + v.z + v.w;
    float q = v.x*v.x + v.y*v.y + v.z*v.z + v.w*v.w;
    #pragma unroll
    for (int off = 32; off; off >>= 1) {
        s += __shfl_xor(s, off);
        q += __shfl_xor(q, off);
    }
    float m = s * (1.f/C_);
    float rstd = rsqrtf(q*(1.f/C_) - m*m + 1e-5f);
    float4 gv = *(const float4*)(gam + lane*4);
    float4 bv = *(const float4*)(bet + lane*4);
    v.x = (v.x - m)*rstd*gv.x + bv.x;
    v.y = (v.y - m)*rstd*gv.y + bv.y;
    v.z = (v.z - m)*rstd*gv.z + bv.z;
    v.w = (v.w - m)*rstd*gv.w + bv.w;
    *(float4*)(xr + lane*4) = v;
}

// ---------------------------------------------------------------------------
// out[b,c,l] = search_feat[b,c,l] + LN2(m2[b,l,:])[c]     (fused residual +
// transpose). 32-row tile in LDS. grid (NS/32, G)
__global__ __launch_bounds__(256)
void final_kernel(const float* __restrict__ m2, const float* __restrict__ sfeat,
                  const float* __restrict__ gam, const float* __restrict__ bet,
                  float* __restrict__ out, int b0)
{
    __shared__ float ms2[32][C_ + 4];
    __shared__ float reds[8][32], redq[8][32];
    __shared__ float mean_s[32], rstd_s[32];
    int g = blockIdx.y, gb = b0 + g;
    int l0 = blockIdx.x * 32;
    int t = threadIdx.x;
    {
        int r = t >> 3, c0 = (t & 7) * 4;
        #pragma unroll
        for (int j = 0; j < 8; ++j)
            *(float4*)&ms2[r][c0 + 32*j] =
                *(const float4*)(m2 + ((size_t)g*NS_ + l0 + r)*C_ + c0 + 32*j);
    }
    __syncthreads();
    {
        int rr = t & 31, part = t >> 5;
        float s = 0.f, q = 0.f;
        #pragma unroll
        for (int j = 0; j < 32; ++j) {
            float v = ms2[rr][part*32 + j];
            s += v; q += v*v;
        }
        reds[part][rr] = s; redq[part][rr] = q;
    }
    __syncthreads();
    if (t < 32) {
        float s = 0.f, q = 0.f;
        #pragma unroll
        for (int p = 0; p < 8; ++p) { s += reds[p][t]; q += redq[p][t]; }
        float m = s * (1.f/C_);
        mean_s[t] = m;
        rstd_s[t] = rsqrtf(q*(1.f/C_) - m*m + 1e-5f);
    }
    __syncthreads();
    int li = t & 31, cg = t >> 5;
    float mn = mean_s[li], rs = rstd_s[li];
    for (int cc = 0; cc < 32; ++cc) {
        int c = cg + 8*cc;
        size_t o = ((size_t)gb*C_ + c)*NS_ + l0 + li;
        float v = sfeat[o] + (ms2[li][c] - mn)*rs*gam[c] + bet[c];
        out[o] = v;
    }
}

// ---------------------------------------------------------------------------
extern "C" void kernel_launch(void* const* d_in, const int* in_sizes, int n_in,
                              void* d_out, int out_size, void* d_ws, size_t ws_size,
                              hipStream_t stream)
{
    (void)in_sizes; (void)n_in; (void)out_size;
    const float* search_feat   = (const float*)d_in[0];
    const float* template_feat = (const float*)d_in[2];
    const float* template_xyz  = (const float*)d_in[3];
    const float* pos_w1  = (const float*)d_in[4];
    const float* pos_b1  = (const float*)d_in[5];
    const float* pos_w2  = (const float*)d_in[6];
    const float* pos_b2  = (const float*)d_in[7];
    const float* q_w     = (const float*)d_in[8];
    const float* k_w     = (const float*)d_in[9];
    const float* v_w     = (const float*)d_in[10];
    const float* merge_w = (const float*)d_in[11];
    const float* mlp_w1  = (const float*)d_in[12];
    const float* mlp_w2  = (const float*)d_in[13];
    const float* ln1_g   = (const float*)d_in[14];
    const float* ln1_b   = (const float*)d_in[15];
    const float* ln2_g   = (const float*)d_in[16];
    const float* ln2_b   = (const float*)d_in[17];
    float* out = (float*)d_out;

    // per-batch workspace: q(NS*C) + msg(NS*C) + kv/merge-out(NS*C) + pos(NT*C) + kvz
    size_t perBatchFloats = (size_t)3*NS_*C_ + (size_t)NT_*C_ + KVZ_;
    int G = 8;
    while (G > 1 && (size_t)G * perBatchFloats * sizeof(float) > ws_size) G >>= 1;

    for (int b0 = 0; b0 < B_; b0 += G) {
        float* qbuf  = (float*)d_ws;                       // [G,NS,C]  Q (elu+1)
        float* mbuf  = qbuf  + (size_t)G*NS_*C_;           // [G,NS,C]  attn msg
        float* kvreg = mbuf  + (size_t)G*NS_*C_;           // [G,NS,C]  k|v, later merge/mlp2 out
        float* kbuf  = kvreg;                              // [G,NT,C]
        float* vbuf  = kvreg + (size_t)G*NT_*C_;           // [G,NT,C]
        float* pbuf  = kvreg + (size_t)G*NS_*C_;           // [G,NT,C]  pos
        float* kvz   = pbuf  + (size_t)G*NT_*C_;           // [G,KVZ_]
        float* hidden = qbuf;                              // [G,NS,2C] overlays q|m

        pos_kernel<<<dim3(NT_/16, G), 256, 0, stream>>>(
            template_xyz, pos_w1, pos_b1, pos_w2, pos_b2, pbuf, b0);
        // Q = elu(sf @ q_w)+1
        gemm_k<1,2><<<dim3(NS_/64, C_/64, G), 256, 0, stream>>>(
            search_feat, nullptr, q_w, qbuf, NS_, C_, C_, b0);
        // K = elu(tf @ k_w)+1
        gemm_k<1,2><<<dim3(NT_/64, C_/64, G), 256, 0, stream>>>(
            template_feat, nullptr, k_w, kbuf, NT_, C_, C_, b0);
        // V = (tf + pos) @ v_w
        gemm_k<2,0><<<dim3(NT_/64, C_/64, G), 256, 0, stream>>>(
            template_feat, pbuf, v_w, vbuf, NT_, C_, C_, b0);
        kv_kernel<<<dim3(H_, G), 256, 0, stream>>>(kbuf, vbuf, kvz);
        attn_kernel<<<dim3(NS_/16, G), 256, 0, stream>>>(qbuf, kvz, mbuf);
        // merge
        gemm_k<0,0><<<dim3(NS_/64, C_/64, G), 256, 0, stream>>>(
            mbuf, nullptr, merge_w, kvreg, NS_, C_, C_, b0);
        ln_kernel<<<dim3(G*NS_/4), 256, 0, stream>>>(kvreg, ln1_g, ln1_b);
        // mlp1: relu(concat[sf, ln1] @ w1)
        gemm_k<3,1><<<dim3(NS_/64, C2_/64, G), 256, 0, stream>>>(
            search_feat, kvreg, mlp_w1, hidden, NS_, C2_, C2_, b0);
        // mlp2
        gemm_k<0,0><<<dim3(NS_/64, C_/64, G), 256, 0, stream>>>(
            hidden, nullptr, mlp_w2, kvreg, NS_, C_, C2_, b0);
        final_kernel<<<dim3(NS_/32, G), 256, 0, stream>>>(
            kvreg, search_feat, ln2_g, ln2_b, out, b0);
    }
}

// Round 2
// 685.036 us; speedup vs baseline: 4.2165x; 4.2165x over previous
//
#include <hip/hip_runtime.h>
#include <math.h>

#define B_  8
#define C_  256
#define NS_ 16384
#define NT_ 8192
#define H_  8
#define D_  32
#define C2_ 512
#define NCH 4
#define KVZ_ (H_*D_*D_ + H_*D_)   // 8448 floats per (batch, chunk)

typedef __attribute__((ext_vector_type(8))) short bf16x8;
typedef __attribute__((ext_vector_type(4))) float f32x4;

__device__ __forceinline__ short f2bf(float f) {
    unsigned u = __float_as_uint(f);
    u = (u + 0x7fffu + ((u >> 16) & 1u)) >> 16;
    return (short)u;
}
__device__ __forceinline__ float bf2f(short s) {
    return __uint_as_float(((unsigned)(unsigned short)s) << 16);
}
__device__ __forceinline__ float2 bfpair(unsigned u) {
    float2 r;
    r.x = __uint_as_float(u << 16);
    r.y = __uint_as_float(u & 0xffff0000u);
    return r;
}
__device__ __forceinline__ void load_lds16(const void* g, void* l) {
    __builtin_amdgcn_global_load_lds(
        (const __attribute__((address_space(1))) unsigned int*)g,
        (__attribute__((address_space(3))) unsigned int*)l, 16, 0, 0);
}

// ---------------------------------------------------------------------------
// transpose-cast: in [B, C, NLEN] f32 -> ob [G, NLEN, C] bf16
__global__ __launch_bounds__(256)
void castT(const float* __restrict__ in, short* __restrict__ ob, int NLEN, int b0)
{
    __shared__ float tl[32][33];
    int g = blockIdx.z, gb = b0 + g;
    int n0 = blockIdx.x * 32, c0 = blockIdx.y * 32;
    int t = threadIdx.x, tr = t >> 5, tc = t & 31;
    #pragma unroll
    for (int i = 0; i < 4; ++i)
        tl[tr + 8*i][tc] = in[((size_t)gb*C_ + c0 + tr + 8*i)*NLEN + n0 + tc];
    __syncthreads();
    #pragma unroll
    for (int i = 0; i < 4; ++i)
        ob[((size_t)g*NLEN + n0 + tr + 8*i)*C_ + c0 + tc] = f2bf(tl[tc][tr + 8*i]);
}

// ---------------------------------------------------------------------------
// weight transpose-cast: w [K,N] f32 -> wt [N,K] bf16 (7 weights in one launch)
struct WDesc { const float* src; int K; int N; int off; };
struct WPack { WDesc d[7]; };

__global__ __launch_bounds__(256)
void wcast_all(WPack p, short* __restrict__ wt)
{
    __shared__ float tl[32][33];
    WDesc d = p.d[blockIdx.z];
    int kt = blockIdx.x * 32, nt = blockIdx.y * 32;
    if (kt >= d.K || nt >= d.N) return;
    int t = threadIdx.x, tr = t >> 5, tc = t & 31;
    #pragma unroll
    for (int i = 0; i < 4; ++i)
        tl[tr + 8*i][tc] = d.src[(size_t)(kt + tr + 8*i)*d.N + nt + tc];
    __syncthreads();
    short* o = wt + d.off;
    #pragma unroll
    for (int i = 0; i < 4; ++i)
        o[(size_t)(nt + tr + 8*i)*d.K + kt + tc] = f2bf(tl[tc][tr + 8*i]);
}

// ---------------------------------------------------------------------------
// h = relu(xyz @ w1 + b1) -> bf16 [G, NT, C]
__global__ __launch_bounds__(256)
void pos_h(const float* __restrict__ xyz, const float* __restrict__ w1,
           const float* __restrict__ b1, short* __restrict__ hb, int b0)
{
    int g = blockIdx.y, gb = b0 + g;
    int r0 = blockIdx.x * 16;
    int t = threadIdx.x;
    float w1x = w1[t], w1y = w1[C_ + t], w1z = w1[2*C_ + t], bb = b1[t];
    for (int r = 0; r < 16; ++r) {
        const float* p = xyz + ((size_t)gb*NT_ + r0 + r)*3;
        float h = fmaxf(p[0]*w1x + p[1]*w1y + p[2]*w1z + bb, 0.f);
        hb[((size_t)g*NT_ + r0 + r)*C_ + t] = f2bf(h);
    }
}

// ---------------------------------------------------------------------------
// bf16 MFMA GEMM (m97 structure): out[g,r,n] = epi( sum_k A(g,r,k) * Wt[n,k] )
// 128x128 tile, BK=32, 4 waves x 4x4 16x16x32 fragments, global_load_lds w16.
// A concat: k < split -> A0 (lda0), else A1 (lda1).
// EPI 0: none, 1: relu, 2: elu+1, 3: + bias[col] + addmat[r,col]
template<int EPI>
__global__ __launch_bounds__(256)
void gemm_bf16(const short* __restrict__ A0, int lda0,
               const short* __restrict__ A1, int lda1, int split,
               const short* __restrict__ Wt,
               const float* __restrict__ bias,
               const short* __restrict__ addmat,
               short* __restrict__ outp,
               int M, int N, int K)
{
    __shared__ __align__(16) short As[128*32];
    __shared__ __align__(16) short Bs[128*32];
    int g = blockIdx.z;
    int nb = blockIdx.x * 128;
    int mb = blockIdx.y * 128;
    int t = threadIdx.x;
    int lane = t & 63;
    int w = t >> 6, wr = w >> 1, wc = w & 1;

    const short* A0g = A0 + (size_t)g*M*lda0;
    const short* A1g = A1 ? (A1 + (size_t)g*M*lda1) : A0;

    f32x4 acc[4][4] = {};

    int r4 = t >> 2;        // 0..63 (tile row in staging)
    int ch = t & 3;         // 16B chunk within 64B row

    for (int kb = 0; kb < K; kb += 32) {
        const short* Ab; int lda, kc;
        if (kb < split) { Ab = A0g; lda = lda0; kc = kb; }
        else            { Ab = A1g; lda = lda1; kc = kb - split; }
        const short* as0 = Ab + (size_t)(mb + r4)*lda + kc + ch*8;
        load_lds16(as0,                   &As[r4*32 + ch*8]);
        load_lds16(as0 + (size_t)64*lda,  &As[(r4 + 64)*32 + ch*8]);
        const short* bs0 = Wt + (size_t)(nb + r4)*K + kb + ch*8;
        load_lds16(bs0,                   &Bs[r4*32 + ch*8]);
        load_lds16(bs0 + (size_t)64*K,    &Bs[(r4 + 64)*32 + ch*8]);
        __syncthreads();

        int kq = (lane >> 4) * 8;
        bf16x8 af[4], bfr[4];
        #pragma unroll
        for (int m = 0; m < 4; ++m)
            af[m] = *(const bf16x8*)&As[(wr*64 + m*16 + (lane & 15))*32 + kq];
        #pragma unroll
        for (int n = 0; n < 4; ++n)
            bfr[n] = *(const bf16x8*)&Bs[(wc*64 + n*16 + (lane & 15))*32 + kq];
        #pragma unroll
        for (int m = 0; m < 4; ++m)
            #pragma unroll
            for (int n = 0; n < 4; ++n)
                acc[m][n] = __builtin_amdgcn_mfma_f32_16x16x32_bf16(
                    af[m], bfr[n], acc[m][n], 0, 0, 0);
        __syncthreads();
    }

    short* og = outp + (size_t)g*M*N;
    const short* am = (EPI == 3) ? (addmat + (size_t)g*M*N) : nullptr;
    int rq = (lane >> 4) * 4;
    int cl = lane & 15;
    #pragma unroll
    for (int m = 0; m < 4; ++m) {
        #pragma unroll
        for (int r = 0; r < 4; ++r) {
            int row = mb + wr*64 + m*16 + rq + r;
            size_t ro = (size_t)row * N;
            #pragma unroll
            for (int n = 0; n < 4; ++n) {
                int col = nb + wc*64 + n*16 + cl;
                float v = acc[m][n][r];
                if constexpr (EPI == 1) v = fmaxf(v, 0.f);
                if constexpr (EPI == 2) v = (v > 0.f) ? (v + 1.f) : __expf(v);
                if constexpr (EPI == 3) v = v + bias[col] + bf2f(am[ro + col]);
                og[ro + col] = f2bf(v);
            }
        }
    }
}

// ---------------------------------------------------------------------------
// KV[h,d,vd] partial sums over NT/NCH rows; Ksum[h,d] likewise. grid (H,NCH,G)
__global__ __launch_bounds__(256)
void kv_kernel(const short* __restrict__ Kb, const short* __restrict__ Vb,
               float* __restrict__ kvz)
{
    __shared__ float SK[32][D_];
    __shared__ float SV[32][D_];
    int h = blockIdx.x, chk = blockIdx.y, g = blockIdx.z;
    int t = threadIdx.x;
    int d = t >> 3, v0 = (t & 7) * 4;
    int lr = t >> 3, lc = (t & 7) * 4;
    float acc[4] = {0.f, 0.f, 0.f, 0.f};
    float ksum = 0.f;
    int s0beg = chk * (NT_/NCH), s0end = s0beg + NT_/NCH;
    for (int s0 = s0beg; s0 < s0end; s0 += 32) {
        size_t off = ((size_t)g*NT_ + s0 + lr)*C_ + h*D_ + lc;
        uint2 ku = *(const uint2*)(Kb + off);
        uint2 vu = *(const uint2*)(Vb + off);
        float2 k0 = bfpair(ku.x), k1 = bfpair(ku.y);
        float2 w0 = bfpair(vu.x), w1 = bfpair(vu.y);
        SK[lr][lc] = k0.x; SK[lr][lc+1] = k0.y; SK[lr][lc+2] = k1.x; SK[lr][lc+3] = k1.y;
        SV[lr][lc] = w0.x; SV[lr][lc+1] = w0.y; SV[lr][lc+2] = w1.x; SV[lr][lc+3] = w1.y;
        __syncthreads();
        #pragma unroll
        for (int ss = 0; ss < 32; ++ss) {
            float kd = SK[ss][d];
            #pragma unroll
            for (int j = 0; j < 4; ++j) acc[j] += kd * SV[ss][v0 + j];
            ksum += kd;
        }
        __syncthreads();
    }
    float* KV = kvz + ((size_t)g*NCH + chk)*KVZ_;
    #pragma unroll
    for (int j = 0; j < 4; ++j) KV[h*D_*D_ + d*D_ + v0 + j] = acc[j];
    if ((t & 7) == 0) KV[H_*D_*D_ + h*D_ + d] = ksum;
}

// ---------------------------------------------------------------------------
// msg[l, h*D+vd] = (sum_d Q*KV) * Z;  Z = 1/(sum_d Q*Ksum + eps). grid (NS/16, G)
__global__ __launch_bounds__(256)
void attn_kernel(const short* __restrict__ Qb, const float* __restrict__ kvz,
                 short* __restrict__ msg)
{
    __shared__ float KVs[H_*D_*D_];
    __shared__ float KSs[H_*D_];
    __shared__ float Qs[16][C_];
    __shared__ float Zs[16][H_];
    int g = blockIdx.y;
    int r0 = blockIdx.x * 16;
    int t = threadIdx.x;
    const float* kvg = kvz + (size_t)g*NCH*KVZ_;
    for (int i = t; i < H_*D_*D_; i += 256) {
        float s = 0.f;
        #pragma unroll
        for (int c = 0; c < NCH; ++c) s += kvg[c*KVZ_ + i];
        KVs[i] = s;
    }
    {
        float s = 0.f;
        #pragma unroll
        for (int c = 0; c < NCH; ++c) s += kvg[c*KVZ_ + H_*D_*D_ + t];
        KSs[t] = s;
    }
    {
        int r = t >> 4, c0 = (t & 15) * 8;
        const short* qrow = Qb + ((size_t)g*NS_ + r0 + r)*C_;
        #pragma unroll
        for (int j = 0; j < 2; ++j) {
            uint4 p = *(const uint4*)(qrow + c0 + 128*j);
            float2 f0 = bfpair(p.x), f1 = bfpair(p.y), f2 = bfpair(p.z), f3 = bfpair(p.w);
            int cb = c0 + 128*j;
            Qs[r][cb+0] = f0.x; Qs[r][cb+1] = f0.y;
            Qs[r][cb+2] = f1.x; Qs[r][cb+3] = f1.y;
            Qs[r][cb+4] = f2.x; Qs[r][cb+5] = f2.y;
            Qs[r][cb+6] = f3.x; Qs[r][cb+7] = f3.y;
        }
    }
    __syncthreads();
    if (t < 128) {
        int r = t >> 3, h = t & 7;
        float qk = 0.f;
        #pragma unroll
        for (int d = 0; d < D_; ++d) qk += Qs[r][h*D_ + d] * KSs[h*D_ + d];
        Zs[r][h] = 1.f / (qk + 1e-6f);
    }
    __syncthreads();
    int h = t >> 5, vd = t & 31;
    const float* kvh = &KVs[h*D_*D_];
    for (int rr = 0; rr < 16; ++rr) {
        float qv = 0.f;
        #pragma unroll
        for (int d = 0; d < D_; ++d) qv += Qs[rr][h*D_ + d] * kvh[d*D_ + vd];
        msg[((size_t)g*NS_ + r0 + rr)*C_ + t] = f2bf(qv * Zs[rr][h]);
    }
}

// ---------------------------------------------------------------------------
// in-place LayerNorm over last dim C, bf16. one wave per row. grid (rows/4)
__global__ __launch_bounds__(256)
void ln_kernel(short* __restrict__ x, const float* __restrict__ gam,
               const float* __restrict__ bet)
{
    int row  = blockIdx.x * 4 + (threadIdx.x >> 6);
    int lane = threadIdx.x & 63;
    short* xr = x + (size_t)row*C_ + lane*4;
    uint2 u = *(const uint2*)xr;
    float2 a = bfpair(u.x), b = bfpair(u.y);
    float s = a.x + a.y + b.x + b.y;
    float q = a.x*a.x + a.y*a.y + b.x*b.x + b.y*b.y;
    #pragma unroll
    for (int off = 32; off; off >>= 1) {
        s += __shfl_xor(s, off);
        q += __shfl_xor(q, off);
    }
    float m = s * (1.f/C_);
    float rstd = rsqrtf(q*(1.f/C_) - m*m + 1e-5f);
    float4 gv = *(const float4*)(gam + lane*4);
    float4 bv = *(const float4*)(bet + lane*4);
    float e0 = (a.x - m)*rstd*gv.x + bv.x;
    float e1 = (a.y - m)*rstd*gv.y + bv.y;
    float e2 = (b.x - m)*rstd*gv.z + bv.z;
    float e3 = (b.y - m)*rstd*gv.w + bv.w;
    uint2 o;
    o.x = (unsigned)(unsigned short)f2bf(e0) | ((unsigned)(unsigned short)f2bf(e1) << 16);
    o.y = (unsigned)(unsigned short)f2bf(e2) | ((unsigned)(unsigned short)f2bf(e3) << 16);
    *(uint2*)xr = o;
}

// ---------------------------------------------------------------------------
// out[b,c,l] = sfeat[b,c,l] + LN2(m2[g,l,:])[c]. grid (NS/32, G)
__global__ __launch_bounds__(256)
void final_kernel(const short* __restrict__ m2, const float* __restrict__ sfeat,
                  const float* __restrict__ gam, const float* __restrict__ bet,
                  float* __restrict__ out, int b0)
{
    __shared__ float ms2[32][C_ + 4];
    __shared__ float reds[8][32], redq[8][32];
    __shared__ float mean_s[32], rstd_s[32];
    int g = blockIdx.y, gb = b0 + g;
    int l0 = blockIdx.x * 32;
    int t = threadIdx.x;
    {
        int r = t >> 3, c0 = (t & 7) * 8;
        const short* row = m2 + ((size_t)g*NS_ + l0 + r)*C_;
        #pragma unroll
        for (int j = 0; j < 4; ++j) {
            uint4 p = *(const uint4*)(row + c0 + 64*j);
            float2 f0 = bfpair(p.x), f1 = bfpair(p.y), f2 = bfpair(p.z), f3 = bfpair(p.w);
            int cb = c0 + 64*j;
            ms2[r][cb+0] = f0.x; ms2[r][cb+1] = f0.y;
            ms2[r][cb+2] = f1.x; ms2[r][cb+3] = f1.y;
            ms2[r][cb+4] = f2.x; ms2[r][cb+5] = f2.y;
            ms2[r][cb+6] = f3.x; ms2[r][cb+7] = f3.y;
        }
    }
    __syncthreads();
    {
        int rr = t & 31, part = t >> 5;
        float s = 0.f, q = 0.f;
        #pragma unroll
        for (int j = 0; j < 32; ++j) {
            float v = ms2[rr][part*32 + j];
            s += v; q += v*v;
        }
        reds[part][rr] = s; redq[part][rr] = q;
    }
    __syncthreads();
    if (t < 32) {
        float s = 0.f, q = 0.f;
        #pragma unroll
        for (int p = 0; p < 8; ++p) { s += reds[p][t]; q += redq[p][t]; }
        float m = s * (1.f/C_);
        mean_s[t] = m;
        rstd_s[t] = rsqrtf(q*(1.f/C_) - m*m + 1e-5f);
    }
    __syncthreads();
    int li = t & 31, cg = t >> 5;
    float mn = mean_s[li], rs = rstd_s[li];
    for (int cc = 0; cc < 32; ++cc) {
        int c = cg + 8*cc;
        size_t o = ((size_t)gb*C_ + c)*NS_ + l0 + li;
        out[o] = sfeat[o] + (ms2[li][c] - mn)*rs*gam[c] + bet[c];
    }
}

// ---------------------------------------------------------------------------
extern "C" void kernel_launch(void* const* d_in, const int* in_sizes, int n_in,
                              void* d_out, int out_size, void* d_ws, size_t ws_size,
                              hipStream_t stream)
{
    (void)in_sizes; (void)n_in; (void)out_size;
    const float* search_feat   = (const float*)d_in[0];
    const float* template_feat = (const float*)d_in[2];
    const float* template_xyz  = (const float*)d_in[3];
    const float* pos_w1  = (const float*)d_in[4];
    const float* pos_b1  = (const float*)d_in[5];
    const float* pos_w2  = (const float*)d_in[6];
    const float* pos_b2  = (const float*)d_in[7];
    const float* q_w     = (const float*)d_in[8];
    const float* k_w     = (const float*)d_in[9];
    const float* v_w     = (const float*)d_in[10];
    const float* merge_w = (const float*)d_in[11];
    const float* mlp_w1  = (const float*)d_in[12];
    const float* mlp_w2  = (const float*)d_in[13];
    const float* ln1_g   = (const float*)d_in[14];
    const float* ln1_b   = (const float*)d_in[15];
    const float* ln2_g   = (const float*)d_in[16];
    const float* ln2_b   = (const float*)d_in[17];
    float* out = (float*)d_out;

    // transposed bf16 weights, packed: q,k,v,merge (256x256), posw2 (256x256),
    // mlp1 (512x512), mlp2 (256x512)
    const int W_Q = 0, W_K = 65536, W_V = 131072, W_M = 196608,
              W_P = 262144, W_1 = 327680, W_2 = 589824;
    const size_t wElems = 720896;

    size_t sfE = (size_t)NS_*C_, tfE = (size_t)NT_*C_;
    int G = 8;
    while (G > 1) {
        size_t shorts = (size_t)G*(5*sfE + 2*tfE) + wElems;
        size_t bytes  = shorts*2 + (size_t)G*NCH*KVZ_*4 + 256;
        if (bytes <= ws_size) break;
        G >>= 1;
    }

    short* wtb  = (short*)d_ws;
    short* sfb  = wtb  + wElems;          // [G,NS,C]  sf bf16
    short* tfb  = sfb  + (size_t)G*sfE;   // [G,NT,C]  tf bf16
    short* tfpb = tfb  + (size_t)G*tfE;   // [G,NT,C]  tf+pos bf16
    short* hid  = tfpb + (size_t)G*tfE;   // [G,NS,2C] hidden; earlier Q|K|V
    short* msgb = hid  + (size_t)2*G*sfE; // [G,NS,C]  h_pos -> msg -> m2
    short* mrgb = msgb + (size_t)G*sfE;   // [G,NS,C]  merge out (LN1 in place)
    float* kvzf = (float*)(mrgb + (size_t)G*sfE);
    short* Qb = hid;
    short* Kb = hid + (size_t)G*sfE;
    short* Vb = hid + (size_t)G*sfE + (size_t)G*tfE;

    WPack pack;
    pack.d[0] = { q_w,     C_,  C_,  W_Q };
    pack.d[1] = { k_w,     C_,  C_,  W_K };
    pack.d[2] = { v_w,     C_,  C_,  W_V };
    pack.d[3] = { merge_w, C_,  C_,  W_M };
    pack.d[4] = { pos_w2,  C_,  C_,  W_P };
    pack.d[5] = { mlp_w1,  C2_, C2_, W_1 };
    pack.d[6] = { mlp_w2,  C2_, C_,  W_2 };
    wcast_all<<<dim3(16, 16, 7), 256, 0, stream>>>(pack, wtb);

    for (int b0 = 0; b0 < B_; b0 += G) {
        castT<<<dim3(NS_/32, C_/32, G), 256, 0, stream>>>(search_feat, sfb, NS_, b0);
        castT<<<dim3(NT_/32, C_/32, G), 256, 0, stream>>>(template_feat, tfb, NT_, b0);
        pos_h<<<dim3(NT_/16, G), 256, 0, stream>>>(template_xyz, pos_w1, pos_b1, msgb, b0);
        // tfp = h @ posw2 + b2 + tf
        gemm_bf16<3><<<dim3(C_/128, NT_/128, G), 256, 0, stream>>>(
            msgb, C_, nullptr, 0, 1<<30, wtb + W_P, pos_b2, tfb, tfpb, NT_, C_, C_);
        // Q = elu(sf @ q_w)+1
        gemm_bf16<2><<<dim3(C_/128, NS_/128, G), 256, 0, stream>>>(
            sfb, C_, nullptr, 0, 1<<30, wtb + W_Q, nullptr, nullptr, Qb, NS_, C_, C_);
        // K = elu(tf @ k_w)+1
        gemm_bf16<2><<<dim3(C_/128, NT_/128, G), 256, 0, stream>>>(
            tfb, C_, nullptr, 0, 1<<30, wtb + W_K, nullptr, nullptr, Kb, NT_, C_, C_);
        // V = tfp @ v_w
        gemm_bf16<0><<<dim3(C_/128, NT_/128, G), 256, 0, stream>>>(
            tfpb, C_, nullptr, 0, 1<<30, wtb + W_V, nullptr, nullptr, Vb, NT_, C_, C_);
        kv_kernel<<<dim3(H_, NCH, G), 256, 0, stream>>>(Kb, Vb, kvzf);
        attn_kernel<<<dim3(NS_/16, G), 256, 0, stream>>>(Qb, kvzf, msgb);
        // merge
        gemm_bf16<0><<<dim3(C_/128, NS_/128, G), 256, 0, stream>>>(
            msgb, C_, nullptr, 0, 1<<30, wtb + W_M, nullptr, nullptr, mrgb, NS_, C_, C_);
        ln_kernel<<<dim3(G*NS_/4), 256, 0, stream>>>(mrgb, ln1_g, ln1_b);
        // hidden = relu([sf | mrg] @ mlp_w1)
        gemm_bf16<1><<<dim3(C2_/128, NS_/128, G), 256, 0, stream>>>(
            sfb, C_, mrgb, C_, C_, wtb + W_1, nullptr, nullptr, hid, NS_, C2_, C2_);
        // m2 = hidden @ mlp_w2
        gemm_bf16<0><<<dim3(C_/128, NS_/128, G), 256, 0, stream>>>(
            hid, C2_, nullptr, 0, 1<<30, wtb + W_2, nullptr, nullptr, msgb, NS_, C_, C2_);
        final_kernel<<<dim3(NS_/32, G), 256, 0, stream>>>(
            msgb, search_feat, ln2_g, ln2_b, out, b0);
    }
}